// Round 12
// baseline (264.620 us; speedup 1.0000x reference)
//
#include <hip/hip_runtime.h>
#include <hip/hip_fp16.h>

// ImplicitPointHead fused (MI355X / gfx950) — round 12
// r11: async B-queue bought only ~5% -> B-latency minor. Ledger: no single
// pipe saturated; residual = per-instruction overhead around 8.4M 16x16 MFMAs.
// This round: 32x32x16 f16 MFMA (half the MFMA instrs, -17% MFMA-pipe time,
// half the wait points). Same wave tile (64pts x 32ch), same asm B-pipeline
// (8-slot single-dwordx4 queue), same raw-barrier overlap. Prep re-layout to
// [ks16][cb32][lane][8]; epilogue uses verified m74/m101 C/D map.

#define NI      128
#define NPTS    2048
#define CH      256
#define NPARAM  263169
#define PT      64
#define NTILES  (NPTS / PT)     // 32
#define ROWS    536             // 67x16B per row (odd -> minimal b128 aliasing)

#define WOFF0   0
#define WOFF1   131072
#define WOFF2   196608
#define WOFF3   262144
#define BOFF0   262400
#define BOFF1   262656
#define BOFF2   262912
#define BOFF3   263168

#define PI_L0   0        // 32 ks16 * 8 cb32 * 64 lane * 8
#define PI_L1   131072   // 16 ks16 * 8 * 512
#define PI_L2   196608
#define PI_L3   262144
#define WS_PER_INST 262400
#define WS_BYTES ((size_t)NI * WS_PER_INST * 2)

typedef __fp16   h16x2  __attribute__((ext_vector_type(2)));
typedef _Float16 f16x8  __attribute__((ext_vector_type(8)));
typedef float    f32x16 __attribute__((ext_vector_type(16)));

union pack8 { h16x2 h[4]; f16x8 v; };

// ---------------- prep: params fp32 -> 32x32-frag-ordered fp16 ----------------
// Frag (ks,cb): lane l covers co = cb*32 + (l&31), k = ks*16 + (l>>5)*8 + j.
__global__ __launch_bounds__(256) void iph_prep(
    const float* __restrict__ params, _Float16* __restrict__ wsw)
{
    const int inst = blockIdx.y;
    const int r = blockIdx.x * 256 + threadIdx.x;
    if (r >= 32800) return;
    const float* __restrict__ P = params + (size_t)inst * NPARAM;
    _Float16* __restrict__ W = wsw + (size_t)inst * WS_PER_INST;

    int rl, woff, K, dst;
    if (r < 16384)      { rl = r;         woff = WOFF0; K = 512; dst = PI_L0; }
    else if (r < 24576) { rl = r - 16384; woff = WOFF1; K = 256; dst = PI_L1; }
    else if (r < 32768) { rl = r - 24576; woff = WOFF2; K = 256; dst = PI_L2; }
    else {
        const int e = (r - 32768) * 8;
        f16x8 v;
        #pragma unroll
        for (int j = 0; j < 8; ++j) v[j] = (_Float16)P[WOFF3 + e + j];
        *(f16x8*)&W[PI_L3 + e] = v;
        return;
    }
    const int e    = rl * 8;
    const int lane = rl & 63;
    const int cb   = (rl >> 6) & 7;
    const int ks   = rl >> 9;
    const int co   = cb * 32 + (lane & 31);
    const int k    = ks * 16 + (lane >> 5) * 8;
    const float* __restrict__ src = P + woff + co * K + k;
    f16x8 v;
    #pragma unroll
    for (int j = 0; j < 8; ++j) v[j] = (_Float16)src[j];
    *(f16x8*)&W[dst + e] = v;
}

// ---------------- asm pipeline primitives ----------------
__device__ __forceinline__ void issue_b1(const _Float16* p, f16x8& r0) {
    const unsigned long long a = (unsigned long long)p;
    asm volatile("global_load_dwordx4 %0, %1, off" : "=&v"(r0) : "v"(a));
}

template<int N>
__device__ __forceinline__ void wait_vm() {
    if constexpr (N >= 7)      asm volatile("s_waitcnt vmcnt(7)" ::: "memory");
    else if constexpr (N == 6) asm volatile("s_waitcnt vmcnt(6)" ::: "memory");
    else if constexpr (N == 5) asm volatile("s_waitcnt vmcnt(5)" ::: "memory");
    else if constexpr (N == 4) asm volatile("s_waitcnt vmcnt(4)" ::: "memory");
    else if constexpr (N == 3) asm volatile("s_waitcnt vmcnt(3)" ::: "memory");
    else if constexpr (N == 2) asm volatile("s_waitcnt vmcnt(2)" ::: "memory");
    else if constexpr (N == 1) asm volatile("s_waitcnt vmcnt(1)" ::: "memory");
    else                       asm volatile("s_waitcnt vmcnt(0)" ::: "memory");
    __builtin_amdgcn_sched_barrier(0);   // rule #18
}

__device__ __forceinline__ void lgkm0_barrier() {
    asm volatile("s_waitcnt lgkmcnt(0)" ::: "memory");
    __builtin_amdgcn_s_barrier();        // raw: vmcnt NOT drained
}

__device__ __forceinline__ void issue_pro8(const _Float16* bp, f16x8 (&q)[8]) {
    #pragma unroll
    for (int i = 0; i < 8; ++i) issue_b1(bp + i * 4096, q[i]);
}

// ---------------- pipelined GEMM, 32x32x16 (asm B-queue, 8 deep) ----------------
// Requires issue_pro8(bp, q) called earlier. NKS = K/16.
template<int NKS>
__device__ __forceinline__ void gemm_pipe(
    f32x16& acc0, f32x16& acc1, const _Float16* bp, const _Float16* ap,
    f16x8 (&q)[8])
{
    #pragma unroll
    for (int ks = 0; ks < NKS; ++ks) {
        f16x8 a0 = *(const f16x8*)(ap + ks * 16);
        f16x8 a1 = *(const f16x8*)(ap + 32 * ROWS + ks * 16);
        const int rem = NKS - 1 - ks;
        if (rem >= 7)      wait_vm<7>();
        else if (rem == 6) wait_vm<6>();
        else if (rem == 5) wait_vm<5>();
        else if (rem == 4) wait_vm<4>();
        else if (rem == 3) wait_vm<3>();
        else if (rem == 2) wait_vm<2>();
        else if (rem == 1) wait_vm<1>();
        else               wait_vm<0>();
        __builtin_amdgcn_s_setprio(1);
        acc0 = __builtin_amdgcn_mfma_f32_32x32x16_f16(a0, q[ks & 7], acc0, 0, 0, 0);
        acc1 = __builtin_amdgcn_mfma_f32_32x32x16_f16(a1, q[ks & 7], acc1, 0, 0, 0);
        __builtin_amdgcn_s_setprio(0);
        if (ks + 8 < NKS)
            issue_b1(bp + (ks + 8) * 4096, q[ks & 7]);
    }
}

// ---------------- main fused kernel ----------------
template<bool PREPPED>
__global__ __launch_bounds__(512, 4) void iph_main(
    const float* __restrict__ feat,     // [128][256][2048]
    const float* __restrict__ coords,   // [128][2048][2]
    const float* __restrict__ params,   // [128][263169]
    const _Float16* __restrict__ wsw,   // fragment-ordered f16 weights
    const float* __restrict__ peg,      // [2][128]
    float* __restrict__ out)            // [128][1][2048]
{
    __shared__ _Float16 X[PT * ROWS];   // 68608 B
    __shared__ float    partial[8][PT]; // 2 KB -> 70.7 KB, 2 blocks/CU

    const int bid  = blockIdx.x;
    const int inst = (bid & 7) | ((bid >> 8) << 3);
    const int tile = (bid >> 3) & 31;
    const int p0   = tile * PT;
    const int tid  = threadIdx.x;
    const int lane = tid & 63;
    const int wave = tid >> 6;
    const int l31  = lane & 31;
    const int sel  = lane >> 5;
    const float* __restrict__ P = params + (size_t)inst * NPARAM;
    const _Float16* __restrict__ WI = wsw + (size_t)inst * WS_PER_INST;

    const _Float16* bp0 = WI + PI_L0 + (wave * 64 + lane) * 8;
    const _Float16* bp1 = WI + PI_L1 + (wave * 64 + lane) * 8;
    const _Float16* bp2 = WI + PI_L2 + (wave * 64 + lane) * 8;
    const _Float16* ap  = &X[l31 * ROWS + sel * 8];

    // hoist all per-lane scalars so no stray global loads sit inside vmcnt regions
    const float bb0 = P[BOFF0 + wave * 32 + l31];
    const float bb1 = P[BOFF1 + wave * 32 + l31];
    const float bb2 = P[BOFF2 + wave * 32 + l31];
    const float w3  = P[WOFF3 + wave * 32 + l31];

    f16x8 qa[8], qb[8], qc[8];

    // L0 B-prologue at kernel top: flies during PE + staging
    if (PREPPED) issue_pro8(bp0, qa);

    // ---- positional encoding -> X[pt][0..255], b128 writes
    {
        const int pt   = tid >> 3;     // 64 pts
        const int part = tid & 7;      // 16 freqs each
        const float2 cc = *(const float2*)&coords[((size_t)inst * NPTS + p0 + pt) * 2];
        const float a = 2.f * cc.x - 1.f;
        const float b = 2.f * cc.y - 1.f;
        float sv[16], cv[16];
        #pragma unroll
        for (int j = 0; j < 16; ++j) {
            const int f = part * 16 + j;
            float locr = a * peg[f] + b * peg[128 + f];
            locr -= floorf(locr);                        // period-1 reduction
            sv[j] = __builtin_amdgcn_sinf(locr);         // sin(2*pi*x)
            cv[j] = __builtin_amdgcn_cosf(locr);
        }
        pack8 q0, q1, c0, c1;
        #pragma unroll
        for (int q = 0; q < 4; ++q) {
            q0.h[q] = __builtin_amdgcn_cvt_pkrtz(sv[2*q],     sv[2*q + 1]);
            q1.h[q] = __builtin_amdgcn_cvt_pkrtz(sv[8 + 2*q], sv[9 + 2*q]);
            c0.h[q] = __builtin_amdgcn_cvt_pkrtz(cv[2*q],     cv[2*q + 1]);
            c1.h[q] = __builtin_amdgcn_cvt_pkrtz(cv[8 + 2*q], cv[9 + 2*q]);
        }
        _Float16* base = &X[pt * ROWS + part * 16];
        *(f16x8*)(base)           = q0.v;
        *(f16x8*)(base + 8)       = q1.v;
        *(f16x8*)(base + 128)     = c0.v;
        *(f16x8*)(base + 136)     = c1.v;
    }
    // ---- features -> X[pt][256..511], 8 dword loads -> one b128 write
    {
        const float* fbase = feat + (size_t)inst * CH * NPTS + p0 + lane;
        #pragma unroll
        for (int s = 0; s < 4; ++s) {
            const int c0i = s * 64 + wave * 8;
            float w8[8];
            #pragma unroll
            for (int j = 0; j < 8; ++j)
                w8[j] = fbase[(size_t)(c0i + j) * NPTS];
            pack8 pk;
            #pragma unroll
            for (int q = 0; q < 4; ++q)
                pk.h[q] = __builtin_amdgcn_cvt_pkrtz(w8[2*q], w8[2*q + 1]);
            *(f16x8*)&X[lane * ROWS + 256 + c0i] = pk.v;
        }
    }
    lgkm0_barrier();   // publish X; raw barrier keeps L0 B-queue in flight

    // epilogue: relu(acc+b) -> X[pt][ch], C/D map (m74/m101):
    // ch = wave*32 + l31 (col), pt = m*32 + (r&3) + 8*(r>>2) + 4*sel
    auto write_epilogue = [&](const f32x16& a0, const f32x16& a1, const float bb) {
        #pragma unroll
        for (int r = 0; r < 16; ++r) {
            const int ptrow = (r & 3) + 8 * (r >> 2) + 4 * sel;
            const float v0 = fmaxf(a0[r] + bb, 0.f);
            const float v1 = fmaxf(a1[r] + bb, 0.f);
            X[ptrow * ROWS + wave * 32 + l31]        = (_Float16)v0;
            X[(32 + ptrow) * ROWS + wave * 32 + l31] = (_Float16)v1;
        }
    };

    // fallback (no prep): convert fp32 weights in-loop, same 32x32 layout
    auto gemm_simple = [&](f32x16& a0c, f32x16& a1c, const float* pw, const int K) {
        for (int ks = 0; ks < (K >> 4); ++ks) {
            const float* wp = pw + (size_t)(wave * 32 + l31) * K + ks * 16 + sel * 8;
            float w8[8];
            __builtin_memcpy(w8, wp, 32);
            f16x8 bf;
            #pragma unroll
            for (int j = 0; j < 8; ++j) bf[j] = (_Float16)w8[j];
            f16x8 a0 = *(const f16x8*)(ap + ks * 16);
            f16x8 a1 = *(const f16x8*)(ap + 32 * ROWS + ks * 16);
            a0c = __builtin_amdgcn_mfma_f32_32x32x16_f16(a0, bf, a0c, 0, 0, 0);
            a1c = __builtin_amdgcn_mfma_f32_32x32x16_f16(a1, bf, a1c, 0, 0, 0);
        }
    };

    const f32x16 zero = {0.f,0.f,0.f,0.f,0.f,0.f,0.f,0.f,0.f,0.f,0.f,0.f,0.f,0.f,0.f,0.f};

    // ---- L0
    {
        f32x16 acc0 = zero, acc1 = zero;
        if (PREPPED) gemm_pipe<32>(acc0, acc1, bp0, ap, qa);
        else         gemm_simple(acc0, acc1, P + WOFF0, 512);
        if (PREPPED) issue_pro8(bp1, qb);      // L1 prologue flies over epilogue
        __builtin_amdgcn_s_barrier();           // all waves done reading X
        write_epilogue(acc0, acc1, bb0);
        lgkm0_barrier();                        // publish L0 output
    }
    // ---- L1
    {
        f32x16 acc0 = zero, acc1 = zero;
        if (PREPPED) gemm_pipe<16>(acc0, acc1, bp1, ap, qb);
        else         gemm_simple(acc0, acc1, P + WOFF1, 256);
        if (PREPPED) issue_pro8(bp2, qc);      // L2 prologue
        __builtin_amdgcn_s_barrier();
        write_epilogue(acc0, acc1, bb1);
        lgkm0_barrier();
    }
    // ---- L2 + L3 fused: partial[wave][pt] = sum_{ch in wave} w3[ch]*relu(acc+b2)
    {
        f32x16 acc0 = zero, acc1 = zero;
        if (PREPPED) gemm_pipe<16>(acc0, acc1, bp2, ap, qc);
        else         gemm_simple(acc0, acc1, P + WOFF2, 256);
        #pragma unroll
        for (int r = 0; r < 16; ++r) {
            const int ptrow = (r & 3) + 8 * (r >> 2) + 4 * sel;
            float s0 = fmaxf(acc0[r] + bb2, 0.f) * w3;
            float s1 = fmaxf(acc1[r] + bb2, 0.f) * w3;
            // reduce over 32 ch = lanes {base..base+31} (xor<=16 stays in half)
            #pragma unroll
            for (int d = 1; d <= 16; d <<= 1) {
                s0 += __shfl_xor(s0, d);
                s1 += __shfl_xor(s1, d);
            }
            if (l31 == 0) {
                partial[wave][ptrow]      = s0;
                partial[wave][32 + ptrow] = s1;
            }
        }
        lgkm0_barrier();                        // publish partials
        if (tid < PT) {
            float s = P[BOFF3];
            #pragma unroll
            for (int w = 0; w < 8; ++w) s += partial[w][tid];
            out[(size_t)inst * NPTS + p0 + tid] = s;
        }
    }
}

extern "C" void kernel_launch(void* const* d_in, const int* in_sizes, int n_in,
                              void* d_out, int out_size, void* d_ws, size_t ws_size,
                              hipStream_t stream) {
    (void)in_sizes; (void)n_in; (void)out_size;
    const float* feat   = (const float*)d_in[0];
    const float* coords = (const float*)d_in[1];
    const float* params = (const float*)d_in[2];
    const float* peg    = (const float*)d_in[3];
    float* out = (float*)d_out;

    dim3 grid(NI * NTILES);   // 4096 blocks
    dim3 block(512);

    if (ws_size >= WS_BYTES) {
        _Float16* wsw = (_Float16*)d_ws;
        iph_prep<<<dim3(129, 128), dim3(256), 0, stream>>>(params, wsw);
        iph_main<true><<<grid, block, 0, stream>>>(feat, coords, params, wsw, peg, out);
    } else {
        iph_main<false><<<grid, block, 0, stream>>>(feat, coords, params,
                                                    (const _Float16*)d_ws, peg, out);
    }
}

// Round 15
// 246.706 us; speedup vs baseline: 1.0726x; 1.0726x over previous
//
#include <hip/hip_runtime.h>
#include <hip/hip_fp16.h>

// ImplicitPointHead fused (MI355X / gfx950) — round 15
// r14 failed on a self-inflicted vmcnt bug: issue_b2 was moved AFTER the wait,
// so in-flight=8 and wait_vm<8> was a no-op -> MFMA consumed unarrived B.
// Fix: issue BEFORE wait (r11 discipline: 10 in flight, vmcnt(8) drains the
// consumed pair). Everything else = r14: wave tile 32ch x 128pts (acc[8][2],
// 16 MFMAs per B-pair), 512 thr, 1 block/CU, asm B-queue, raw barriers.

#define NI      128
#define NPTS    2048
#define CH      256
#define NPARAM  263169
#define PT      128
#define NTILES  (NPTS / PT)     // 16
#define ROWS    536             // 67x16B per row (odd -> minimal b128 aliasing)

#define WOFF0   0
#define WOFF1   131072
#define WOFF2   196608
#define WOFF3   262144
#define BOFF0   262400
#define BOFF1   262656
#define BOFF2   262912
#define BOFF3   263168

#define PI_L0   0        // 16 ks * 16 cb * 64 lane * 8
#define PI_L1   131072
#define PI_L2   196608
#define PI_L3   262144
#define WS_PER_INST 262400
#define WS_BYTES ((size_t)NI * WS_PER_INST * 2)

typedef __fp16   h16x2 __attribute__((ext_vector_type(2)));
typedef _Float16 f16x8 __attribute__((ext_vector_type(8)));
typedef float    f32x4 __attribute__((ext_vector_type(4)));

union pack8 { h16x2 h[4]; f16x8 v; };

// ---------------- prep: params fp32 -> fragment-ordered fp16 (r11) ----------------
// Frag cb, lane l covers co = (cb>>1)*32 + 2*(l&15) + (cb&1); k = ks*32+(l>>4)*8.
__global__ __launch_bounds__(256) void iph_prep(
    const float* __restrict__ params, _Float16* __restrict__ wsw)
{
    const int inst = blockIdx.y;
    const int r = blockIdx.x * 256 + threadIdx.x;
    if (r >= 32800) return;
    const float* __restrict__ P = params + (size_t)inst * NPARAM;
    _Float16* __restrict__ W = wsw + (size_t)inst * WS_PER_INST;

    int rl, woff, K, dst;
    if (r < 16384)      { rl = r;         woff = WOFF0; K = 512; dst = PI_L0; }
    else if (r < 24576) { rl = r - 16384; woff = WOFF1; K = 256; dst = PI_L1; }
    else if (r < 32768) { rl = r - 24576; woff = WOFF2; K = 256; dst = PI_L2; }
    else {
        const int e = (r - 32768) * 8;
        f16x8 v;
        #pragma unroll
        for (int j = 0; j < 8; ++j) v[j] = (_Float16)P[WOFF3 + e + j];
        *(f16x8*)&W[PI_L3 + e] = v;
        return;
    }
    const int e    = rl * 8;
    const int lane = rl & 63;
    const int cb   = (rl >> 6) & 15;
    const int ks   = rl >> 10;
    const int co   = (cb >> 1) * 32 + 2 * (lane & 15) + (cb & 1);
    const int k    = ks * 32 + (lane >> 4) * 8;
    const float* __restrict__ src = P + woff + co * K + k;
    f16x8 v;
    #pragma unroll
    for (int j = 0; j < 8; ++j) v[j] = (_Float16)src[j];
    *(f16x8*)&W[dst + e] = v;
}

// ---------------- asm pipeline primitives (r11, unchanged) ----------------
__device__ __forceinline__ void issue_b2(const _Float16* p, f16x8& r0, f16x8& r1) {
    const unsigned long long a = (unsigned long long)p;
    asm volatile("global_load_dwordx4 %0, %2, off\n\t"
                 "global_load_dwordx4 %1, %2, off offset:1024"
                 : "=&v"(r0), "=&v"(r1)
                 : "v"(a));
}

template<int N>
__device__ __forceinline__ void wait_vm() {
    if constexpr (N >= 8)      asm volatile("s_waitcnt vmcnt(8)" ::: "memory");
    else if constexpr (N == 6) asm volatile("s_waitcnt vmcnt(6)" ::: "memory");
    else if constexpr (N == 4) asm volatile("s_waitcnt vmcnt(4)" ::: "memory");
    else if constexpr (N == 2) asm volatile("s_waitcnt vmcnt(2)" ::: "memory");
    else                       asm volatile("s_waitcnt vmcnt(0)" ::: "memory");
    __builtin_amdgcn_sched_barrier(0);   // rule #18
}

__device__ __forceinline__ void lgkm0_barrier() {
    asm volatile("s_waitcnt lgkmcnt(0)" ::: "memory");
    __builtin_amdgcn_s_barrier();        // raw: vmcnt NOT drained
}

__device__ __forceinline__ void issue_pro(const _Float16* bp, f16x8 (&b0s)[5], f16x8 (&b1s)[5]) {
    #pragma unroll
    for (int i = 0; i < 4; ++i)
        issue_b2(bp + i * 8192, b0s[i], b1s[i]);
}

// ---------------- pipelined GEMM (asm B-queue; wave = 32ch x 128pts) ----------------
// Requires issue_pro(bp,...) earlier (pairs 0..3 in flight).
template<int NKS>
__device__ __forceinline__ void gemm_pipe(
    f32x4 (&acc)[8][2], const _Float16* bp, const _Float16* ap,
    f16x8 (&b0s)[5], f16x8 (&b1s)[5])
{
    #pragma unroll
    for (int ks = 0; ks < NKS; ++ks) {
        f16x8 a[8];
        #pragma unroll
        for (int mt = 0; mt < 8; ++mt)
            a[mt] = *(const f16x8*)(ap + mt * 16 * ROWS + ks * 32);
        // ISSUE FIRST (r11 discipline): in flight = pairs ks..ks+4 (10 loads)
        if (ks + 4 < NKS)
            issue_b2(bp + (ks + 4) * 8192, b0s[(ks + 4) % 5], b1s[(ks + 4) % 5]);
        // then wait: vmcnt(8) drains exactly pair ks
        const int rem = NKS - 1 - ks;
        if (rem >= 4)      wait_vm<8>();
        else if (rem == 3) wait_vm<6>();
        else if (rem == 2) wait_vm<4>();
        else if (rem == 1) wait_vm<2>();
        else               wait_vm<0>();
        __builtin_amdgcn_s_setprio(1);
        #pragma unroll
        for (int mt = 0; mt < 8; ++mt) {
            acc[mt][0] = __builtin_amdgcn_mfma_f32_16x16x32_f16(a[mt], b0s[ks % 5], acc[mt][0], 0, 0, 0);
            acc[mt][1] = __builtin_amdgcn_mfma_f32_16x16x32_f16(a[mt], b1s[ks % 5], acc[mt][1], 0, 0, 0);
        }
        __builtin_amdgcn_s_setprio(0);
    }
}

// ---------------- main fused kernel (512 threads, PT=128) ----------------
template<bool PREPPED>
__global__ __launch_bounds__(512) void iph_main(
    const float* __restrict__ feat,     // [128][256][2048]
    const float* __restrict__ coords,   // [128][2048][2]
    const float* __restrict__ params,   // [128][263169]
    const _Float16* __restrict__ wsw,   // fragment-ordered f16 weights
    const float* __restrict__ peg,      // [2][128]
    float* __restrict__ out)            // [128][1][2048]
{
    __shared__ _Float16 X[PT * ROWS];   // 137216 B
    __shared__ float    partial[8][PT]; // 4 KB -> 141312 B, 1 block/CU, 8 waves

    const int bid  = blockIdx.x;        // 2048 blocks
    const int inst = (bid & 7) | ((bid >> 7) << 3);   // inst's 16 tiles on one XCD
    const int tile = (bid >> 3) & 15;
    const int p0   = tile * PT;
    const int tid  = threadIdx.x;
    const int lane = tid & 63;
    const int wave = tid >> 6;          // 0..7, owns ch wave*32..wave*32+31
    const int l15  = lane & 15;
    const int hi   = lane >> 4;
    const float* __restrict__ P = params + (size_t)inst * NPARAM;
    const _Float16* __restrict__ WI = wsw + (size_t)inst * WS_PER_INST;

    const _Float16* bp0 = WI + PI_L0 + ((wave * 2) * 64 + lane) * 8;
    const _Float16* bp1 = WI + PI_L1 + ((wave * 2) * 64 + lane) * 8;
    const _Float16* bp2 = WI + PI_L2 + ((wave * 2) * 64 + lane) * 8;
    const _Float16* ap  = &X[l15 * ROWS + hi * 8];

    // hoist per-lane scalars (keeps vmcnt regions clean)
    const float2 bb0 = *(const float2*)&P[BOFF0 + wave * 32 + 2 * l15];
    const float2 bb1 = *(const float2*)&P[BOFF1 + wave * 32 + 2 * l15];
    const float2 bb2 = *(const float2*)&P[BOFF2 + wave * 32 + 2 * l15];
    const float2 w3  = *(const float2*)&P[WOFF3 + wave * 32 + 2 * l15];

    f16x8 s0[5], s1[5], t0[5], t1[5], u0[5], u1[5];

    // L0 B-prologue at kernel top: flies during PE + staging
    if (PREPPED) issue_pro(bp0, s0, s1);

    // ---- positional encoding -> X[pt][0..255]  (4 threads/pt, 32 freqs each)
    {
        const int pt   = tid >> 2;     // 0..127
        const int part = tid & 3;      // 32 freqs each
        const float2 cc = *(const float2*)&coords[((size_t)inst * NPTS + p0 + pt) * 2];
        const float a = 2.f * cc.x - 1.f;
        const float b = 2.f * cc.y - 1.f;
        float sv[32], cv[32];
        #pragma unroll
        for (int j = 0; j < 32; ++j) {
            const int f = part * 32 + j;
            float locr = a * peg[f] + b * peg[128 + f];
            locr -= floorf(locr);                        // period-1 reduction
            sv[j] = __builtin_amdgcn_sinf(locr);         // sin(2*pi*x)
            cv[j] = __builtin_amdgcn_cosf(locr);
        }
        _Float16* base = &X[pt * ROWS + part * 32];
        #pragma unroll
        for (int c = 0; c < 4; ++c) {
            pack8 ps, pc;
            #pragma unroll
            for (int q = 0; q < 4; ++q) {
                ps.h[q] = __builtin_amdgcn_cvt_pkrtz(sv[c*8 + 2*q], sv[c*8 + 2*q + 1]);
                pc.h[q] = __builtin_amdgcn_cvt_pkrtz(cv[c*8 + 2*q], cv[c*8 + 2*q + 1]);
            }
            *(f16x8*)(base + c * 8)       = ps.v;
            *(f16x8*)(base + 128 + c * 8) = pc.v;
        }
    }
    // ---- features -> X[pt][256..511]; thread: pt = tid&127, 64 ch (8xb128)
    {
        const int p  = tid & 127;
        const int cg = tid >> 7;       // 0..3 -> channels cg*64..cg*64+63
        const float* fbase = feat + (size_t)inst * CH * NPTS + (size_t)(cg * 64) * NPTS + p0 + p;
        #pragma unroll
        for (int s = 0; s < 8; ++s) {
            float w8[8];
            #pragma unroll
            for (int j = 0; j < 8; ++j)
                w8[j] = fbase[(size_t)(s * 8 + j) * NPTS];
            pack8 pk;
            #pragma unroll
            for (int q = 0; q < 4; ++q)
                pk.h[q] = __builtin_amdgcn_cvt_pkrtz(w8[2*q], w8[2*q + 1]);
            *(f16x8*)&X[p * ROWS + 256 + cg * 64 + s * 8] = pk.v;
        }
    }
    lgkm0_barrier();   // publish X; raw barrier keeps L0 B-queue in flight

    // epilogue: relu(acc+b) -> X (even/odd half2 writes); C/D map (m89)
    auto write_epilogue = [&](f32x4 (&acc)[8][2], const float2 bb) {
        #pragma unroll
        for (int mt = 0; mt < 8; ++mt) {
            #pragma unroll
            for (int r = 0; r < 4; ++r) {
                const float v0 = fmaxf(acc[mt][0][r] + bb.x, 0.f);
                const float v1 = fmaxf(acc[mt][1][r] + bb.y, 0.f);
                const h16x2 e = __builtin_amdgcn_cvt_pkrtz(v0, v1);
                const int pt = mt * 16 + hi * 4 + r;
                *(h16x2*)&X[pt * ROWS + wave * 32 + 2 * l15] = e;
            }
        }
    };

    // fallback (no prep): r6-style simple path, mt widened to 8
    auto gemm_simple = [&](f32x4 (&acc)[8][2], const float* pw, const int K) {
        for (int ks = 0; ks < (K >> 5); ++ks) {
            f16x8 bfrag[2];
            #pragma unroll
            for (int nt = 0; nt < 2; ++nt) {
                const int co = wave * 32 + 2 * l15 + nt;
                const float* wp = pw + (size_t)co * K + ks * 32 + hi * 8;
                float w8[8];
                __builtin_memcpy(w8, wp, 32);
                f16x8 bb;
                #pragma unroll
                for (int j = 0; j < 8; ++j) bb[j] = (_Float16)w8[j];
                bfrag[nt] = bb;
            }
            #pragma unroll
            for (int mt = 0; mt < 8; ++mt) {
                f16x8 af = *(const f16x8*)&X[(mt * 16 + l15) * ROWS + ks * 32 + hi * 8];
                acc[mt][0] = __builtin_amdgcn_mfma_f32_16x16x32_f16(af, bfrag[0], acc[mt][0], 0, 0, 0);
                acc[mt][1] = __builtin_amdgcn_mfma_f32_16x16x32_f16(af, bfrag[1], acc[mt][1], 0, 0, 0);
            }
        }
    };

    // ---- L0
    {
        f32x4 acc[8][2];
        #pragma unroll
        for (int mt = 0; mt < 8; ++mt)
            #pragma unroll
            for (int nt = 0; nt < 2; ++nt)
                acc[mt][nt] = (f32x4){0.f, 0.f, 0.f, 0.f};
        if (PREPPED) gemm_pipe<16>(acc, bp0, ap, s0, s1);
        else         gemm_simple(acc, P + WOFF0, 512);
        if (PREPPED) issue_pro(bp1, t0, t1);   // L1 prologue flies over epilogue
        __builtin_amdgcn_s_barrier();           // all waves done reading X
        write_epilogue(acc, bb0);
        lgkm0_barrier();                        // publish L0 output
    }
    // ---- L1
    {
        f32x4 acc[8][2];
        #pragma unroll
        for (int mt = 0; mt < 8; ++mt)
            #pragma unroll
            for (int nt = 0; nt < 2; ++nt)
                acc[mt][nt] = (f32x4){0.f, 0.f, 0.f, 0.f};
        if (PREPPED) gemm_pipe<8>(acc, bp1, ap, t0, t1);
        else         gemm_simple(acc, P + WOFF1, 256);
        if (PREPPED) issue_pro(bp2, u0, u1);   // L2 prologue
        __builtin_amdgcn_s_barrier();
        write_epilogue(acc, bb1);
        lgkm0_barrier();
    }
    // ---- L2 + L3 fused: partial[wave][pt] = sum_{ch in wave} w3[ch]*relu(acc+b2)
    {
        f32x4 acc[8][2];
        #pragma unroll
        for (int mt = 0; mt < 8; ++mt)
            #pragma unroll
            for (int nt = 0; nt < 2; ++nt)
                acc[mt][nt] = (f32x4){0.f, 0.f, 0.f, 0.f};
        if (PREPPED) gemm_pipe<8>(acc, bp2, ap, u0, u1);
        else         gemm_simple(acc, P + WOFF2, 256);
        #pragma unroll
        for (int mt = 0; mt < 8; ++mt) {
            #pragma unroll
            for (int r = 0; r < 4; ++r) {
                const float v0 = fmaxf(acc[mt][0][r] + bb2.x, 0.f);
                const float v1 = fmaxf(acc[mt][1][r] + bb2.y, 0.f);
                float s = v0 * w3.x + v1 * w3.y;
                s += __shfl_xor(s, 1);
                s += __shfl_xor(s, 2);
                s += __shfl_xor(s, 4);
                s += __shfl_xor(s, 8);
                if (l15 == 0)
                    partial[wave][mt * 16 + hi * 4 + r] = s;
            }
        }
        lgkm0_barrier();                        // publish partials
        if (tid < PT) {
            float s = P[BOFF3];
            #pragma unroll
            for (int w = 0; w < 8; ++w) s += partial[w][tid];
            out[(size_t)inst * NPTS + p0 + tid] = s;
        }
    }
}

extern "C" void kernel_launch(void* const* d_in, const int* in_sizes, int n_in,
                              void* d_out, int out_size, void* d_ws, size_t ws_size,
                              hipStream_t stream) {
    (void)in_sizes; (void)n_in; (void)out_size;
    const float* feat   = (const float*)d_in[0];
    const float* coords = (const float*)d_in[1];
    const float* params = (const float*)d_in[2];
    const float* peg    = (const float*)d_in[3];
    float* out = (float*)d_out;

    dim3 grid(NI * NTILES);   // 2048 blocks
    dim3 block(512);

    if (ws_size >= WS_BYTES) {
        _Float16* wsw = (_Float16*)d_ws;
        iph_prep<<<dim3(129, 128), dim3(256), 0, stream>>>(params, wsw);
        iph_main<true><<<grid, block, 0, stream>>>(feat, coords, params, wsw, peg, out);
    } else {
        iph_main<false><<<grid, block, 0, stream>>>(feat, coords, params,
                                                    (const _Float16*)d_ws, peg, out);
    }
}